// Round 5
// baseline (284.057 us; speedup 1.0000x reference)
//
#include <hip/hip_runtime.h>
#include <hip/hip_fp16.h>

#define DIM 64

// ---------------- helpers: half2 <-> float punning ----------------
__device__ __forceinline__ float2 h2f(unsigned int u) {
    __half2 h = *reinterpret_cast<__half2*>(&u);
    return __half22float2(h);
}
__device__ __forceinline__ unsigned int f2h(float a, float b) {
    __half2 h = __floats2half2_rn(a, b);
    return *reinterpret_cast<unsigned int*>(&h);
}

// ---------------- edge dtype detection + conversion + degree ----------------
__device__ __forceinline__ bool edges_are_i64(const unsigned int* w) {
    unsigned int acc = 0;
#pragma unroll
    for (int k = 0; k < 8; ++k) acc |= w[2 * k + 1];
    return acc == 0;
}

__global__ void k_convert_deg(const void* ei_raw, int* edges, int* deg, int E) {
    int i = blockIdx.x * blockDim.x + threadIdx.x;
    int n2 = 2 * E;
    if (i >= n2) return;
    const unsigned int* w = (const unsigned int*)ei_raw;
    bool is64 = edges_are_i64(w);
    int v = is64 ? (int)(((const long long*)ei_raw)[i]) : ((const int*)ei_raw)[i];
    edges[i] = v;
    if (i >= E) atomicAdd(&deg[v], 1);  // dst degree
}

// ---------------- y0 = fp16(dinv * emb)  (8 elems / thread) -----------------
__global__ void k_tohalf_scaled(const float* __restrict__ x, const float* __restrict__ dinv,
                                __half* __restrict__ yh, int n8) {
    int i = blockIdx.x * blockDim.x + threadIdx.x;
    if (i >= n8) return;
    int node = i >> 3;  // 8 chunks of 8 per 64-wide row
    float di = dinv[node];
    const float4* p = (const float4*)(x + (size_t)i * 8);
    float4 a = p[0], b = p[1];
    uint4 o;
    o.x = f2h(di * a.x, di * a.y); o.y = f2h(di * a.z, di * a.w);
    o.z = f2h(di * b.x, di * b.y); o.w = f2h(di * b.z, di * b.w);
    ((uint4*)yh)[i] = o;
}

// ---------------- exclusive scan of deg -> rowptr (+ fused dinv) ------------
__global__ void k_scan1(const int* __restrict__ deg, int* __restrict__ rowptr,
                        int* __restrict__ bsum, float* __restrict__ dinv, int N) {
    __shared__ int sh[256];
    int i = blockIdx.x * 256 + threadIdx.x;
    int v = (i < N) ? deg[i] : 0;
    if (i < N) dinv[i] = v > 0 ? 1.0f / sqrtf((float)v) : 0.0f;
    sh[threadIdx.x] = v;
    __syncthreads();
    for (int o = 1; o < 256; o <<= 1) {
        int t = (threadIdx.x >= o) ? sh[threadIdx.x - o] : 0;
        __syncthreads();
        sh[threadIdx.x] += t;
        __syncthreads();
    }
    if (i < N) rowptr[i] = sh[threadIdx.x] - v;  // exclusive
    if (threadIdx.x == 255) bsum[blockIdx.x] = sh[255];
}

__global__ void k_scan2(int* __restrict__ bsum, int nb) {
    __shared__ int sh[1024];
    int tid = threadIdx.x;
    int v = (tid < nb) ? bsum[tid] : 0;
    sh[tid] = v;
    __syncthreads();
    for (int o = 1; o < 1024; o <<= 1) {
        int t = (tid >= o) ? sh[tid - o] : 0;
        __syncthreads();
        sh[tid] += t;
        __syncthreads();
    }
    if (tid < nb) bsum[tid] = sh[tid] - v;
}

__global__ void k_scan3(int* __restrict__ rowptr, const int* __restrict__ bsum,
                        int* __restrict__ cursor, int N, int E) {
    int i = blockIdx.x * blockDim.x + threadIdx.x;
    if (i < N) {
        int r = rowptr[i] + bsum[i >> 8];
        rowptr[i] = r;
        cursor[i] = r;
    }
    if (i == 0) rowptr[N] = E;
}

// ---------------- counting-sort fill: CSR by destination (src only) ---------
__global__ void k_fill(const int* __restrict__ edges, int* __restrict__ cursor,
                       int* __restrict__ esrc, int E) {
    int e = blockIdx.x * blockDim.x + threadIdx.x;
    if (e >= E) return;
    int s = edges[e];
    int d = edges[E + e];
    int pos = atomicAdd(&cursor[d], 1);
    esrc[pos] = s;
}

// ---------------- gather layer (pull, y-space fp16, fused accumulation) -----
// y = dinv*x iterate. 8 lanes per node; lane c owns halves [8c, 8c+8).
// S[d] = sum_e y[src_e]  (f32 accum)
// x[d] = dinv[d]*S ; ynext[d] = dinv[d]^2*S
// out: first -> out = a0*emb + a*x        (f32)
//      mid   -> out += a*x                (f32)
//      last  -> outh = fp16(out + a*x)
__global__ void k_gather_y(const int* __restrict__ rowptr, const int* __restrict__ esrc,
                           const float* __restrict__ dinv, const __half* __restrict__ ysrc,
                           __half* __restrict__ ynext, float* __restrict__ out,
                           __half* __restrict__ outh, const float* __restrict__ emb,
                           const float* __restrict__ alpha, int aidx,
                           int first, int last, int N) {
    int t = blockIdx.x * blockDim.x + threadIdx.x;
    int node = t >> 3, c = t & 7;
    if (node >= N) return;
    int beg = rowptr[node], end = rowptr[node + 1];
    float acc[8] = {0.f, 0.f, 0.f, 0.f, 0.f, 0.f, 0.f, 0.f};
    for (int i = beg; i < end; ++i) {
        int s = esrc[i];
        uint4 u = ((const uint4*)(ysrc + (size_t)s * DIM))[c];
        float2 f0 = h2f(u.x), f1 = h2f(u.y), f2 = h2f(u.z), f3 = h2f(u.w);
        acc[0] += f0.x; acc[1] += f0.y;
        acc[2] += f1.x; acc[3] += f1.y;
        acc[4] += f2.x; acc[5] += f2.y;
        acc[6] += f3.x; acc[7] += f3.y;
    }
    float di = dinv[node];
    float a = alpha[aidx] * di;       // folds x = di*S into the alpha step

    if (!last) {
        float d2 = di * di;
        uint4 o;
        o.x = f2h(d2 * acc[0], d2 * acc[1]); o.y = f2h(d2 * acc[2], d2 * acc[3]);
        o.z = f2h(d2 * acc[4], d2 * acc[5]); o.w = f2h(d2 * acc[6], d2 * acc[7]);
        ((uint4*)(ynext + (size_t)node * DIM))[c] = o;
    }

    float o[8];
    if (first) {
        float a0 = alpha[0];
        const float4* ep = (const float4*)(emb + (size_t)node * DIM + c * 8);
        float4 e0 = ep[0], e1 = ep[1];
        o[0] = a0 * e0.x; o[1] = a0 * e0.y; o[2] = a0 * e0.z; o[3] = a0 * e0.w;
        o[4] = a0 * e1.x; o[5] = a0 * e1.y; o[6] = a0 * e1.z; o[7] = a0 * e1.w;
    } else {
        const float4* op = (const float4*)(out + (size_t)node * DIM + c * 8);
        float4 e0 = op[0], e1 = op[1];
        o[0] = e0.x; o[1] = e0.y; o[2] = e0.z; o[3] = e0.w;
        o[4] = e1.x; o[5] = e1.y; o[6] = e1.z; o[7] = e1.w;
    }
#pragma unroll
    for (int k = 0; k < 8; ++k) o[k] += a * acc[k];

    if (last) {
        uint4 u;
        u.x = f2h(o[0], o[1]); u.y = f2h(o[2], o[3]);
        u.z = f2h(o[4], o[5]); u.w = f2h(o[6], o[7]);
        ((uint4*)(outh + (size_t)node * DIM))[c] = u;
    } else {
        float4* op = (float4*)(out + (size_t)node * DIM + c * 8);
        op[0] = make_float4(o[0], o[1], o[2], o[3]);
        op[1] = make_float4(o[4], o[5], o[6], o[7]);
    }
}

// ---------------- final: res[e] = dot(outh[src], outh[dst]) -----------------
__global__ void k_final_h(const int* __restrict__ edges, const __half* __restrict__ outh,
                          float* __restrict__ res, int E) {
    int t = blockIdx.x * blockDim.x + threadIdx.x;
    int e = t >> 3, c = t & 7;
    if (e >= E) return;
    int s = edges[e];
    int d = edges[E + e];
    uint4 ua = ((const uint4*)(outh + (size_t)s * DIM))[c];
    uint4 ub = ((const uint4*)(outh + (size_t)d * DIM))[c];
    float2 a0 = h2f(ua.x), a1 = h2f(ua.y), a2 = h2f(ua.z), a3 = h2f(ua.w);
    float2 b0 = h2f(ub.x), b1 = h2f(ub.y), b2 = h2f(ub.z), b3 = h2f(ub.w);
    float p = a0.x * b0.x + a0.y * b0.y + a1.x * b1.x + a1.y * b1.y +
              a2.x * b2.x + a2.y * b2.y + a3.x * b3.x + a3.y * b3.y;
    p += __shfl_down(p, 4, 8);
    p += __shfl_down(p, 2, 8);
    p += __shfl_down(p, 1, 8);
    if (c == 0) res[e] = p;
}

static inline size_t alignUp(size_t x) { return (x + 511) & ~size_t(511); }

extern "C" void kernel_launch(void* const* d_in, const int* in_sizes, int n_in,
                              void* d_out, int out_size, void* d_ws, size_t ws_size,
                              hipStream_t stream) {
    const void*  ei    = d_in[0];
    const float* emb   = (const float*)d_in[1];
    const float* alpha = (const float*)d_in[2];
    float*       res   = (float*)d_out;

    const int E = in_sizes[0] / 2;       // 1,000,000
    const int N = in_sizes[1] / DIM;     // 150,000
    const int NUM_LAYERS = 3;

    // ---- carve workspace ----
    char* w = (char*)d_ws;
    size_t off = 0;
    int*    edges  = (int*)(w + off);    off = alignUp(off + (size_t)2 * E * sizeof(int));
    int*    deg    = (int*)(w + off);    off = alignUp(off + (size_t)N * sizeof(int));  // -> cursor
    float*  dinv   = (float*)(w + off);  off = alignUp(off + (size_t)N * sizeof(float));
    int*    rowptr = (int*)(w + off);    off = alignUp(off + (size_t)(N + 1) * sizeof(int));
    int*    bsum   = (int*)(w + off);    off = alignUp(off + (size_t)1024 * sizeof(int));
    int*    esrc   = (int*)(w + off);    off = alignUp(off + (size_t)E * sizeof(int));
    float*  outv   = (float*)(w + off);  off = alignUp(off + (size_t)N * DIM * sizeof(float));
    __half* y0h    = (__half*)(w + off); off = alignUp(off + (size_t)N * DIM * sizeof(__half));
    __half* xAh    = (__half*)(w + off); off = alignUp(off + (size_t)N * DIM * sizeof(__half));
    __half* xBh    = (__half*)(w + off); off = alignUp(off + (size_t)N * DIM * sizeof(__half));
    __half* outh   = (__half*)(w + off); off = alignUp(off + (size_t)N * DIM * sizeof(__half));
    (void)ws_size;

    const int B = 256;
    const int n2 = 2 * E;
    const int nb = (N + 255) / 256;      // 586 <= 1024
    const int n8 = N * DIM / 8;

    hipMemsetAsync(deg, 0, (size_t)N * sizeof(int), stream);
    k_convert_deg<<<(n2 + B - 1) / B, B, 0, stream>>>(ei, edges, deg, E);

    k_scan1<<<nb, 256, 0, stream>>>(deg, rowptr, bsum, dinv, N);
    k_scan2<<<1, 1024, 0, stream>>>(bsum, nb);
    k_scan3<<<(N + B - 1) / B, B, 0, stream>>>(rowptr, bsum, deg /*cursor*/, N, E);

    k_tohalf_scaled<<<(n8 + B - 1) / B, B, 0, stream>>>(emb, dinv, y0h, n8);
    k_fill<<<(E + B - 1) / B, B, 0, stream>>>(edges, deg /*cursor*/, esrc, E);

    // ---- 3 gather layers (y-space fp16) ----
    long long tN8 = (long long)N * 8;
    int ggrid = (int)((tN8 + B - 1) / B);
    const __half* yc = y0h;
    __half* bufs[2] = {xAh, xBh};
    for (int i = 0; i < NUM_LAYERS; ++i) {
        __half* yn = bufs[i & 1];
        int last = (i == NUM_LAYERS - 1) ? 1 : 0;
        k_gather_y<<<ggrid, B, 0, stream>>>(rowptr, esrc, dinv, yc, yn, outv, outh,
                                            emb, alpha, i + 1, (i == 0) ? 1 : 0, last, N);
        yc = yn;
    }

    // ---- final dots, original edge order ----
    long long tE8 = (long long)E * 8;
    k_final_h<<<(int)((tE8 + B - 1) / B), B, 0, stream>>>(edges, outh, res, E);
}

// Round 6
// 269.010 us; speedup vs baseline: 1.0559x; 1.0559x over previous
//
#include <hip/hip_runtime.h>
#include <hip/hip_fp16.h>

#define DIM 64
#define PCHUNK 2048

// ---------------- helpers: half2 <-> float punning ----------------
__device__ __forceinline__ float2 h2f(unsigned int u) {
    __half2 h = *reinterpret_cast<__half2*>(&u);
    return __half22float2(h);
}
__device__ __forceinline__ unsigned int f2h(float a, float b) {
    __half2 h = __floats2half2_rn(a, b);
    return *reinterpret_cast<unsigned int*>(&h);
}

// ---------------- edge dtype detection + conversion + degree ----------------
__device__ __forceinline__ bool edges_are_i64(const unsigned int* w) {
    unsigned int acc = 0;
#pragma unroll
    for (int k = 0; k < 8; ++k) acc |= w[2 * k + 1];
    return acc == 0;
}

__global__ void k_convert_deg(const void* ei_raw, int* edges, int* deg, int E) {
    int i = blockIdx.x * blockDim.x + threadIdx.x;
    int n2 = 2 * E;
    if (i >= n2) return;
    const unsigned int* w = (const unsigned int*)ei_raw;
    bool is64 = edges_are_i64(w);
    int v = is64 ? (int)(((const long long*)ei_raw)[i]) : ((const int*)ei_raw)[i];
    edges[i] = v;
    if (i >= E) atomicAdd(&deg[v], 1);  // dst degree
}

// ---------------- y0 = fp16(dinv * emb)  (8 elems / thread) -----------------
__global__ void k_tohalf_scaled(const float* __restrict__ x, const float* __restrict__ dinv,
                                __half* __restrict__ yh, int n8) {
    int i = blockIdx.x * blockDim.x + threadIdx.x;
    if (i >= n8) return;
    int node = i >> 3;
    float di = dinv[node];
    const float4* p = (const float4*)(x + (size_t)i * 8);
    float4 a = p[0], b = p[1];
    uint4 o;
    o.x = f2h(di * a.x, di * a.y); o.y = f2h(di * a.z, di * a.w);
    o.z = f2h(di * b.x, di * b.y); o.w = f2h(di * b.z, di * b.w);
    ((uint4*)yh)[i] = o;
}

// ---------------- exclusive scan of deg -> rowptr (+ fused dinv) ------------
__global__ void k_scan1(const int* __restrict__ deg, int* __restrict__ rowptr,
                        int* __restrict__ bsum, float* __restrict__ dinv, int N) {
    __shared__ int sh[256];
    int i = blockIdx.x * 256 + threadIdx.x;
    int v = (i < N) ? deg[i] : 0;
    if (i < N) dinv[i] = v > 0 ? 1.0f / sqrtf((float)v) : 0.0f;
    sh[threadIdx.x] = v;
    __syncthreads();
    for (int o = 1; o < 256; o <<= 1) {
        int t = (threadIdx.x >= o) ? sh[threadIdx.x - o] : 0;
        __syncthreads();
        sh[threadIdx.x] += t;
        __syncthreads();
    }
    if (i < N) rowptr[i] = sh[threadIdx.x] - v;
    if (threadIdx.x == 255) bsum[blockIdx.x] = sh[255];
}

__global__ void k_scan2(int* __restrict__ bsum, int nb) {
    __shared__ int sh[1024];
    int tid = threadIdx.x;
    int v = (tid < nb) ? bsum[tid] : 0;
    sh[tid] = v;
    __syncthreads();
    for (int o = 1; o < 1024; o <<= 1) {
        int t = (tid >= o) ? sh[tid - o] : 0;
        __syncthreads();
        sh[tid] += t;
        __syncthreads();
    }
    if (tid < nb) bsum[tid] = sh[tid] - v;
}

__global__ void k_scan3(int* __restrict__ rowptr, const int* __restrict__ bsum,
                        int* __restrict__ cursor, int N, int E) {
    int i = blockIdx.x * blockDim.x + threadIdx.x;
    if (i < N) {
        int r = rowptr[i] + bsum[i >> 8];
        rowptr[i] = r;
        cursor[i] = r;
    }
    if (i == 0) rowptr[N] = E;
}

// ---------------- bucket cursors from rowptr --------------------------------
__global__ void k_bcur(const int* __restrict__ rowptr, int* __restrict__ bcur,
                       int NB, int SH) {
    int b = threadIdx.x;
    if (b < NB) bcur[b] = rowptr[b << SH];
}

// ---------------- pass A: partition edges into dst-buckets ------------------
// Records (s,d) land in pe[] at their bucket's CSR range (intra-bucket order
// arbitrary). LDS staging -> near-coalesced flush.
__global__ void k_partition(const int* __restrict__ edges, int E, int NB, int SH,
                            int* __restrict__ bcur, uint2* __restrict__ pe) {
    __shared__ int cnt[128], lstart[128], gb[128], lofs[128];
    __shared__ uint2 stage[PCHUNK];
    __shared__ int gpos[PCHUNK];
    int base = blockIdx.x * PCHUNK;
    int n = E - base; if (n > PCHUNK) n = PCHUNK;
    for (int b = threadIdx.x; b < NB; b += 256) { cnt[b] = 0; lofs[b] = 0; }
    __syncthreads();
    int s[8], d[8], bk[8];
#pragma unroll
    for (int r = 0; r < 8; ++r) {
        int i = r * 256 + threadIdx.x;
        if (i < n) {
            s[r] = edges[base + i];
            d[r] = edges[E + base + i];
            bk[r] = d[r] >> SH;
            atomicAdd(&cnt[bk[r]], 1);
        }
    }
    __syncthreads();
    if (threadIdx.x == 0) {
        int run = 0;
        for (int b = 0; b < NB; ++b) { lstart[b] = run; run += cnt[b]; }
    }
    __syncthreads();
    for (int b = threadIdx.x; b < NB; b += 256)
        if (cnt[b] > 0) gb[b] = atomicAdd(&bcur[b], cnt[b]);
    __syncthreads();
#pragma unroll
    for (int r = 0; r < 8; ++r) {
        int i = r * 256 + threadIdx.x;
        if (i < n) {
            int b = bk[r];
            int j = atomicAdd(&lofs[b], 1);
            int slot = lstart[b] + j;
            stage[slot] = make_uint2((unsigned)s[r], (unsigned)d[r]);
            gpos[slot] = gb[b] + j;
        }
    }
    __syncthreads();
    for (int i = threadIdx.x; i < n; i += 256)
        pe[gpos[i]] = stage[i];
}

// ---------------- pass B: fine counting-sort inside buckets -----------------
// Contiguous i -> same bucket -> cursor window ~8KB, esrc window ~54KB (L2-hot).
// Bijective XCD swizzle keeps each bucket's window on one XCD's L2.
__global__ void k_fill2(const uint2* __restrict__ pe, int* __restrict__ cursor,
                        int* __restrict__ esrc, int E, int nwg) {
    int bid = blockIdx.x;
    int q = nwg >> 3, r = nwg & 7;
    int xcd = bid & 7, k = bid >> 3;
    int wg = (xcd < r ? xcd * (q + 1) : r * (q + 1) + (xcd - r) * q) + k;
    int i = wg * 256 + threadIdx.x;
    if (i >= E) return;
    uint2 rec = pe[i];
    int pos = atomicAdd(&cursor[(int)rec.y], 1);
    esrc[pos] = (int)rec.x;
}

// ---------------- gather layer (pull, y-space fp16, fused accumulation) -----
__global__ void k_gather_y(const int* __restrict__ rowptr, const int* __restrict__ esrc,
                           const float* __restrict__ dinv, const __half* __restrict__ ysrc,
                           __half* __restrict__ ynext, float* __restrict__ out,
                           __half* __restrict__ outh, const float* __restrict__ emb,
                           const float* __restrict__ alpha, int aidx,
                           int first, int last, int N) {
    int t = blockIdx.x * blockDim.x + threadIdx.x;
    int node = t >> 3, c = t & 7;
    if (node >= N) return;
    int beg = rowptr[node], end = rowptr[node + 1];
    float acc[8] = {0.f, 0.f, 0.f, 0.f, 0.f, 0.f, 0.f, 0.f};
    for (int i = beg; i < end; ++i) {
        int s = esrc[i];
        uint4 u = ((const uint4*)(ysrc + (size_t)s * DIM))[c];
        float2 f0 = h2f(u.x), f1 = h2f(u.y), f2 = h2f(u.z), f3 = h2f(u.w);
        acc[0] += f0.x; acc[1] += f0.y;
        acc[2] += f1.x; acc[3] += f1.y;
        acc[4] += f2.x; acc[5] += f2.y;
        acc[6] += f3.x; acc[7] += f3.y;
    }
    float di = dinv[node];
    float a = alpha[aidx] * di;

    if (!last) {
        float d2 = di * di;
        uint4 o;
        o.x = f2h(d2 * acc[0], d2 * acc[1]); o.y = f2h(d2 * acc[2], d2 * acc[3]);
        o.z = f2h(d2 * acc[4], d2 * acc[5]); o.w = f2h(d2 * acc[6], d2 * acc[7]);
        ((uint4*)(ynext + (size_t)node * DIM))[c] = o;
    }

    float o[8];
    if (first) {
        float a0 = alpha[0];
        const float4* ep = (const float4*)(emb + (size_t)node * DIM + c * 8);
        float4 e0 = ep[0], e1 = ep[1];
        o[0] = a0 * e0.x; o[1] = a0 * e0.y; o[2] = a0 * e0.z; o[3] = a0 * e0.w;
        o[4] = a0 * e1.x; o[5] = a0 * e1.y; o[6] = a0 * e1.z; o[7] = a0 * e1.w;
    } else {
        const float4* op = (const float4*)(out + (size_t)node * DIM + c * 8);
        float4 e0 = op[0], e1 = op[1];
        o[0] = e0.x; o[1] = e0.y; o[2] = e0.z; o[3] = e0.w;
        o[4] = e1.x; o[5] = e1.y; o[6] = e1.z; o[7] = e1.w;
    }
#pragma unroll
    for (int k = 0; k < 8; ++k) o[k] += a * acc[k];

    if (last) {
        uint4 u;
        u.x = f2h(o[0], o[1]); u.y = f2h(o[2], o[3]);
        u.z = f2h(o[4], o[5]); u.w = f2h(o[6], o[7]);
        ((uint4*)(outh + (size_t)node * DIM))[c] = u;
    } else {
        float4* op = (float4*)(out + (size_t)node * DIM + c * 8);
        op[0] = make_float4(o[0], o[1], o[2], o[3]);
        op[1] = make_float4(o[4], o[5], o[6], o[7]);
    }
}

// ---------------- final: res[e] = dot(outh[src], outh[dst]) -----------------
__global__ void k_final_h(const int* __restrict__ edges, const __half* __restrict__ outh,
                          float* __restrict__ res, int E) {
    int t = blockIdx.x * blockDim.x + threadIdx.x;
    int e = t >> 3, c = t & 7;
    if (e >= E) return;
    int s = edges[e];
    int d = edges[E + e];
    uint4 ua = ((const uint4*)(outh + (size_t)s * DIM))[c];
    uint4 ub = ((const uint4*)(outh + (size_t)d * DIM))[c];
    float2 a0 = h2f(ua.x), a1 = h2f(ua.y), a2 = h2f(ua.z), a3 = h2f(ua.w);
    float2 b0 = h2f(ub.x), b1 = h2f(ub.y), b2 = h2f(ub.z), b3 = h2f(ub.w);
    float p = a0.x * b0.x + a0.y * b0.y + a1.x * b1.x + a1.y * b1.y +
              a2.x * b2.x + a2.y * b2.y + a3.x * b3.x + a3.y * b3.y;
    p += __shfl_down(p, 4, 8);
    p += __shfl_down(p, 2, 8);
    p += __shfl_down(p, 1, 8);
    if (c == 0) res[e] = p;
}

static inline size_t alignUp(size_t x) { return (x + 511) & ~size_t(511); }

extern "C" void kernel_launch(void* const* d_in, const int* in_sizes, int n_in,
                              void* d_out, int out_size, void* d_ws, size_t ws_size,
                              hipStream_t stream) {
    const void*  ei    = d_in[0];
    const float* emb   = (const float*)d_in[1];
    const float* alpha = (const float*)d_in[2];
    float*       res   = (float*)d_out;

    const int E = in_sizes[0] / 2;       // 1,000,000
    const int N = in_sizes[1] / DIM;     // 150,000
    const int NUM_LAYERS = 3;

    // bucket geometry: NB <= 128
    int SH = 11;
    int NB = (N + (1 << SH) - 1) >> SH;
    while (NB > 128) { SH++; NB = (N + (1 << SH) - 1) >> SH; }

    // ---- carve workspace ----
    char* w = (char*)d_ws;
    size_t off = 0;
    int*    edges  = (int*)(w + off);    off = alignUp(off + (size_t)2 * E * sizeof(int));
    int*    deg    = (int*)(w + off);    off = alignUp(off + (size_t)N * sizeof(int));  // -> cursor
    float*  dinv   = (float*)(w + off);  off = alignUp(off + (size_t)N * sizeof(float));
    int*    rowptr = (int*)(w + off);    off = alignUp(off + (size_t)(N + 1) * sizeof(int));
    int*    bsum   = (int*)(w + off);    off = alignUp(off + (size_t)1024 * sizeof(int));
    int*    bcur   = (int*)(w + off);    off = alignUp(off + (size_t)128 * sizeof(int));
    int*    esrc   = (int*)(w + off);    off = alignUp(off + (size_t)E * sizeof(int));
    uint2*  pe     = (uint2*)(w + off);  off = alignUp(off + (size_t)E * sizeof(uint2));
    float*  outv   = (float*)(w + off);  off = alignUp(off + (size_t)N * DIM * sizeof(float));
    __half* y0h    = (__half*)(w + off); off = alignUp(off + (size_t)N * DIM * sizeof(__half));
    __half* xAh    = (__half*)(w + off); off = alignUp(off + (size_t)N * DIM * sizeof(__half));
    __half* xBh    = (__half*)(w + off); off = alignUp(off + (size_t)N * DIM * sizeof(__half));
    __half* outh   = (__half*)(w + off); off = alignUp(off + (size_t)N * DIM * sizeof(__half));
    (void)ws_size;

    const int B = 256;
    const int n2 = 2 * E;
    const int nb = (N + 255) / 256;      // 586 <= 1024
    const int n8 = N * DIM / 8;

    hipMemsetAsync(deg, 0, (size_t)N * sizeof(int), stream);
    k_convert_deg<<<(n2 + B - 1) / B, B, 0, stream>>>(ei, edges, deg, E);

    k_scan1<<<nb, 256, 0, stream>>>(deg, rowptr, bsum, dinv, N);
    k_scan2<<<1, 1024, 0, stream>>>(bsum, nb);
    k_scan3<<<(N + B - 1) / B, B, 0, stream>>>(rowptr, bsum, deg /*cursor*/, N, E);
    k_bcur<<<1, 128, 0, stream>>>(rowptr, bcur, NB, SH);

    k_tohalf_scaled<<<(n8 + B - 1) / B, B, 0, stream>>>(emb, dinv, y0h, n8);

    // two-phase bucketed CSR fill
    int npart = (E + PCHUNK - 1) / PCHUNK;
    k_partition<<<npart, 256, 0, stream>>>(edges, E, NB, SH, bcur, pe);
    int nwg = (E + B - 1) / B;
    k_fill2<<<nwg, B, 0, stream>>>(pe, deg /*cursor*/, esrc, E, nwg);

    // ---- 3 gather layers (y-space fp16) ----
    long long tN8 = (long long)N * 8;
    int ggrid = (int)((tN8 + B - 1) / B);
    const __half* yc = y0h;
    __half* bufs[2] = {xAh, xBh};
    for (int i = 0; i < NUM_LAYERS; ++i) {
        __half* yn = bufs[i & 1];
        int last = (i == NUM_LAYERS - 1) ? 1 : 0;
        k_gather_y<<<ggrid, B, 0, stream>>>(rowptr, esrc, dinv, yc, yn, outv, outh,
                                            emb, alpha, i + 1, (i == 0) ? 1 : 0, last, N);
        yc = yn;
    }

    // ---- final dots, original edge order ----
    long long tE8 = (long long)E * 8;
    k_final_h<<<(int)((tE8 + B - 1) / B), B, 0, stream>>>(edges, outh, res, E);
}

// Round 7
// 193.111 us; speedup vs baseline: 1.4709x; 1.3930x over previous
//
#include <hip/hip_runtime.h>
#include <hip/hip_fp16.h>

#define DIM 64
#define PCHUNK 2048
#define BSH 9                   // 512 nodes per bucket
#define BNODES (1 << BSH)

// ---------------- helpers: half2 <-> float punning ----------------
__device__ __forceinline__ float2 h2f(unsigned int u) {
    __half2 h = *reinterpret_cast<__half2*>(&u);
    return __half22float2(h);
}
__device__ __forceinline__ unsigned int f2h(float a, float b) {
    __half2 h = __floats2half2_rn(a, b);
    return *reinterpret_cast<unsigned int*>(&h);
}

// ---------------- edge dtype detection (int64 vs int32) ----------------
__device__ __forceinline__ bool edges_are_i64(const unsigned int* w) {
    unsigned int acc = 0;
#pragma unroll
    for (int k = 0; k < 8; ++k) acc |= w[2 * k + 1];
    return acc == 0;
}
__device__ __forceinline__ int ld_edge(const void* raw, bool is64, size_t idx) {
    return is64 ? (int)((const long long*)raw)[idx] : ((const int*)raw)[idx];
}

// ---------------- pass A: partition raw edges into dst-bucket windows -------
// pe window for bucket b = [b*CAP, b*CAP + bwcnt[b]). Conversion fused.
__global__ void k_partition(const void* ei_raw, int E, int NB, int CAP,
                            int* __restrict__ bwcnt, uint2* __restrict__ pe) {
    __shared__ int cnt[512], lstart[512], gb[512], lofs[512], psum[256];
    __shared__ uint2 stage[PCHUNK];
    __shared__ int gpos[PCHUNK];
    bool is64 = edges_are_i64((const unsigned int*)ei_raw);
    int base = blockIdx.x * PCHUNK;
    int n = E - base; if (n > PCHUNK) n = PCHUNK;
    int t = threadIdx.x;
    for (int b = t; b < 512; b += 256) { cnt[b] = 0; lofs[b] = 0; }
    __syncthreads();
    int s[8], d[8];
#pragma unroll
    for (int r = 0; r < 8; ++r) {
        int i = r * 256 + t;
        if (i < n) {
            s[r] = ld_edge(ei_raw, is64, (size_t)base + i);
            d[r] = ld_edge(ei_raw, is64, (size_t)E + base + i);
            atomicAdd(&cnt[d[r] >> BSH], 1);
        }
    }
    __syncthreads();
    // parallel exclusive scan of cnt[512] with 256 threads (pair trick)
    int a0 = cnt[2 * t], a1 = cnt[2 * t + 1];
    psum[t] = a0 + a1;
    __syncthreads();
    int v = psum[t];
    for (int o = 1; o < 256; o <<= 1) {
        int tv = (t >= o) ? psum[t - o] : 0;
        __syncthreads();
        psum[t] += tv;
        __syncthreads();
    }
    int excl = psum[t] - v;
    lstart[2 * t] = excl;
    lstart[2 * t + 1] = excl + a0;
    __syncthreads();
    for (int b = t; b < NB; b += 256)
        if (cnt[b] > 0) gb[b] = atomicAdd(&bwcnt[b], cnt[b]);
    __syncthreads();
#pragma unroll
    for (int r = 0; r < 8; ++r) {
        int i = r * 256 + t;
        if (i < n) {
            int b = d[r] >> BSH;
            int j = atomicAdd(&lofs[b], 1);
            int slot = lstart[b] + j;
            stage[slot] = make_uint2((unsigned)s[r], (unsigned)d[r]);
            int gj = gb[b] + j;
            // overflow guard (prob ~0): dump into spare region past NB*CAP
            gpos[slot] = (gj < CAP) ? (b * CAP + gj) : (NB * CAP + slot);
        }
    }
    __syncthreads();
    for (int i = t; i < n; i += 256)
        pe[gpos[i]] = stage[i];
}

// ---------------- scan bucket counts -> CSR bucket bases --------------------
__global__ void k_bscan(const int* __restrict__ bwcnt, int* __restrict__ ebase, int NB) {
    __shared__ int sh[512];
    int tid = threadIdx.x;
    int v = (tid < NB) ? bwcnt[tid] : 0;
    sh[tid] = v;
    __syncthreads();
    for (int o = 1; o < 512; o <<= 1) {
        int t2 = (tid >= o) ? sh[tid - o] : 0;
        __syncthreads();
        sh[tid] += t2;
        __syncthreads();
    }
    if (tid < NB) ebase[tid] = sh[tid] - v;          // exclusive
    if (tid == NB - 1) ebase[NB] = sh[tid];          // total
}

// ---------------- pass B: per-bucket deg/rowptr/dinv/esrc, all LDS-local ----
__global__ void k_bucket(const uint2* __restrict__ pe, const int* __restrict__ bwcnt,
                         const int* __restrict__ ebase, int CAP,
                         int* __restrict__ rowptr, float* __restrict__ dinv,
                         int* __restrict__ esrc, int N, int E, int NB) {
    __shared__ int ldeg[BNODES], lcur[BNODES], psum[256];
    int b = blockIdx.x;
    int n0 = b << BSH;
    int nn = N - n0; if (nn > BNODES) nn = BNODES;
    int ecnt = bwcnt[b];
    int eb = ebase[b];
    const uint2* win = pe + (size_t)b * CAP;
    int t = threadIdx.x;
    for (int j = t; j < BNODES; j += 256) ldeg[j] = 0;
    __syncthreads();
    for (int i = t; i < ecnt; i += 256)
        atomicAdd(&ldeg[win[i].y - n0], 1);
    __syncthreads();
    // exclusive scan of ldeg[512] with 256 threads
    int a0 = ldeg[2 * t], a1 = ldeg[2 * t + 1];
    psum[t] = a0 + a1;
    __syncthreads();
    int v = psum[t];
    for (int o = 1; o < 256; o <<= 1) {
        int tv = (t >= o) ? psum[t - o] : 0;
        __syncthreads();
        psum[t] += tv;
        __syncthreads();
    }
    int excl = psum[t] - v;
    int e0 = excl, e1 = excl + a0;
    lcur[2 * t] = e0;
    lcur[2 * t + 1] = e1;
    if (2 * t < nn) {
        rowptr[n0 + 2 * t] = eb + e0;
        dinv[n0 + 2 * t] = a0 > 0 ? 1.0f / sqrtf((float)a0) : 0.0f;
    }
    if (2 * t + 1 < nn) {
        rowptr[n0 + 2 * t + 1] = eb + e1;
        dinv[n0 + 2 * t + 1] = a1 > 0 ? 1.0f / sqrtf((float)a1) : 0.0f;
    }
    if (b == NB - 1 && t == 0) rowptr[N] = E;
    __syncthreads();
    for (int i = t; i < ecnt; i += 256) {
        uint2 rec = win[i];
        int pos = eb + atomicAdd(&lcur[rec.y - n0], 1);
        esrc[pos] = (int)rec.x;
    }
}

// ---------------- y0 = fp16(dinv * emb)  (8 elems / thread) -----------------
__global__ void k_tohalf_scaled(const float* __restrict__ x, const float* __restrict__ dinv,
                                __half* __restrict__ yh, int n8) {
    int i = blockIdx.x * blockDim.x + threadIdx.x;
    if (i >= n8) return;
    int node = i >> 3;
    float di = dinv[node];
    const float4* p = (const float4*)(x + (size_t)i * 8);
    float4 a = p[0], b = p[1];
    uint4 o;
    o.x = f2h(di * a.x, di * a.y); o.y = f2h(di * a.z, di * a.w);
    o.z = f2h(di * b.x, di * b.y); o.w = f2h(di * b.z, di * b.w);
    ((uint4*)yh)[i] = o;
}

// ---------------- gather layer (pull, y-space fp16, fused accumulation) -----
__global__ void k_gather_y(const int* __restrict__ rowptr, const int* __restrict__ esrc,
                           const float* __restrict__ dinv, const __half* __restrict__ ysrc,
                           __half* __restrict__ ynext, float* __restrict__ out,
                           __half* __restrict__ outh, const float* __restrict__ emb,
                           const float* __restrict__ alpha, int aidx,
                           int first, int last, int N) {
    int t = blockIdx.x * blockDim.x + threadIdx.x;
    int node = t >> 3, c = t & 7;
    if (node >= N) return;
    int beg = rowptr[node], end = rowptr[node + 1];
    float acc[8] = {0.f, 0.f, 0.f, 0.f, 0.f, 0.f, 0.f, 0.f};
    for (int i = beg; i < end; ++i) {
        int s = esrc[i];
        uint4 u = ((const uint4*)(ysrc + (size_t)s * DIM))[c];
        float2 f0 = h2f(u.x), f1 = h2f(u.y), f2 = h2f(u.z), f3 = h2f(u.w);
        acc[0] += f0.x; acc[1] += f0.y;
        acc[2] += f1.x; acc[3] += f1.y;
        acc[4] += f2.x; acc[5] += f2.y;
        acc[6] += f3.x; acc[7] += f3.y;
    }
    float di = dinv[node];
    float a = alpha[aidx] * di;

    if (!last) {
        float d2 = di * di;
        uint4 o;
        o.x = f2h(d2 * acc[0], d2 * acc[1]); o.y = f2h(d2 * acc[2], d2 * acc[3]);
        o.z = f2h(d2 * acc[4], d2 * acc[5]); o.w = f2h(d2 * acc[6], d2 * acc[7]);
        ((uint4*)(ynext + (size_t)node * DIM))[c] = o;
    }

    float o[8];
    if (first) {
        float a0 = alpha[0];
        const float4* ep = (const float4*)(emb + (size_t)node * DIM + c * 8);
        float4 e0 = ep[0], e1 = ep[1];
        o[0] = a0 * e0.x; o[1] = a0 * e0.y; o[2] = a0 * e0.z; o[3] = a0 * e0.w;
        o[4] = a0 * e1.x; o[5] = a0 * e1.y; o[6] = a0 * e1.z; o[7] = a0 * e1.w;
    } else {
        const float4* op = (const float4*)(out + (size_t)node * DIM + c * 8);
        float4 e0 = op[0], e1 = op[1];
        o[0] = e0.x; o[1] = e0.y; o[2] = e0.z; o[3] = e0.w;
        o[4] = e1.x; o[5] = e1.y; o[6] = e1.z; o[7] = e1.w;
    }
#pragma unroll
    for (int k = 0; k < 8; ++k) o[k] += a * acc[k];

    if (last) {
        uint4 u;
        u.x = f2h(o[0], o[1]); u.y = f2h(o[2], o[3]);
        u.z = f2h(o[4], o[5]); u.w = f2h(o[6], o[7]);
        ((uint4*)(outh + (size_t)node * DIM))[c] = u;
    } else {
        float4* op = (float4*)(out + (size_t)node * DIM + c * 8);
        op[0] = make_float4(o[0], o[1], o[2], o[3]);
        op[1] = make_float4(o[4], o[5], o[6], o[7]);
    }
}

// ---------------- final: res[e] = dot(outh[src], outh[dst]), raw edges ------
__global__ void k_final_h(const void* ei_raw, const __half* __restrict__ outh,
                          float* __restrict__ res, int E) {
    bool is64 = edges_are_i64((const unsigned int*)ei_raw);
    int t = blockIdx.x * blockDim.x + threadIdx.x;
    int e = t >> 3, c = t & 7;
    if (e >= E) return;
    int s = ld_edge(ei_raw, is64, (size_t)e);
    int d = ld_edge(ei_raw, is64, (size_t)E + e);
    uint4 ua = ((const uint4*)(outh + (size_t)s * DIM))[c];
    uint4 ub = ((const uint4*)(outh + (size_t)d * DIM))[c];
    float2 a0 = h2f(ua.x), a1 = h2f(ua.y), a2 = h2f(ua.z), a3 = h2f(ua.w);
    float2 b0 = h2f(ub.x), b1 = h2f(ub.y), b2 = h2f(ub.z), b3 = h2f(ub.w);
    float p = a0.x * b0.x + a0.y * b0.y + a1.x * b1.x + a1.y * b1.y +
              a2.x * b2.x + a2.y * b2.y + a3.x * b3.x + a3.y * b3.y;
    p += __shfl_down(p, 4, 8);
    p += __shfl_down(p, 2, 8);
    p += __shfl_down(p, 1, 8);
    if (c == 0) res[e] = p;
}

static inline size_t alignUp(size_t x) { return (x + 511) & ~size_t(511); }

extern "C" void kernel_launch(void* const* d_in, const int* in_sizes, int n_in,
                              void* d_out, int out_size, void* d_ws, size_t ws_size,
                              hipStream_t stream) {
    const void*  ei    = d_in[0];
    const float* emb   = (const float*)d_in[1];
    const float* alpha = (const float*)d_in[2];
    float*       res   = (float*)d_out;

    const int E = in_sizes[0] / 2;       // 1,000,000
    const int N = in_sizes[1] / DIM;     // 150,000
    const int NUM_LAYERS = 3;

    // bucket geometry
    const int NB = (N + BNODES - 1) >> BSH;           // 293 (<= 512)
    int cap = (E / NB) * 3 / 2;                       // mean*1.5
    const int CAP = (cap + 1023) & ~1023;             // 5120

    // ---- carve workspace ----
    char* w = (char*)d_ws;
    size_t off = 0;
    int*    bwcnt  = (int*)(w + off);    off = alignUp(off + (size_t)(NB + 1) * sizeof(int));
    int*    ebase  = (int*)(w + off);    off = alignUp(off + (size_t)(NB + 1) * sizeof(int));
    float*  dinv   = (float*)(w + off);  off = alignUp(off + (size_t)N * sizeof(float));
    int*    rowptr = (int*)(w + off);    off = alignUp(off + (size_t)(N + 1) * sizeof(int));
    int*    esrc   = (int*)(w + off);    off = alignUp(off + (size_t)E * sizeof(int));
    uint2*  pe     = (uint2*)(w + off);  off = alignUp(off + ((size_t)NB * CAP + PCHUNK) * sizeof(uint2));
    float*  outv   = (float*)(w + off);  off = alignUp(off + (size_t)N * DIM * sizeof(float));
    __half* y0h    = (__half*)(w + off); off = alignUp(off + (size_t)N * DIM * sizeof(__half));
    __half* xAh    = (__half*)(w + off); off = alignUp(off + (size_t)N * DIM * sizeof(__half));
    __half* xBh    = (__half*)(w + off); off = alignUp(off + (size_t)N * DIM * sizeof(__half));
    __half* outh   = (__half*)(w + off); off = alignUp(off + (size_t)N * DIM * sizeof(__half));
    (void)ws_size;

    const int B = 256;
    const int n8 = N * DIM / 8;

    hipMemsetAsync(bwcnt, 0, (size_t)(NB + 1) * sizeof(int), stream);

    int npart = (E + PCHUNK - 1) / PCHUNK;
    k_partition<<<npart, 256, 0, stream>>>(ei, E, NB, CAP, bwcnt, pe);
    k_bscan<<<1, 512, 0, stream>>>(bwcnt, ebase, NB);
    k_bucket<<<NB, 256, 0, stream>>>(pe, bwcnt, ebase, CAP, rowptr, dinv, esrc, N, E, NB);

    k_tohalf_scaled<<<(n8 + B - 1) / B, B, 0, stream>>>(emb, dinv, y0h, n8);

    // ---- 3 gather layers (y-space fp16) ----
    long long tN8 = (long long)N * 8;
    int ggrid = (int)((tN8 + B - 1) / B);
    const __half* yc = y0h;
    __half* bufs[2] = {xAh, xBh};
    for (int i = 0; i < NUM_LAYERS; ++i) {
        __half* yn = bufs[i & 1];
        int last = (i == NUM_LAYERS - 1) ? 1 : 0;
        k_gather_y<<<ggrid, B, 0, stream>>>(rowptr, esrc, dinv, yc, yn, outv, outh,
                                            emb, alpha, i + 1, (i == 0) ? 1 : 0, last, N);
        yc = yn;
    }

    // ---- final dots, original edge order, raw edge reads ----
    long long tE8 = (long long)E * 8;
    k_final_h<<<(int)((tE8 + B - 1) / B), B, 0, stream>>>(ei, outh, res, E);
}